// Round 8
// baseline (453.832 us; speedup 1.0000x reference)
//
#include <hip/hip_runtime.h>

#define DFEAT 64
#define SCAN_B 1024

__device__ __forceinline__ float bf2f(unsigned short u) {
    return __uint_as_float(((unsigned)u) << 16);
}
__device__ __forceinline__ unsigned short f2bf(float f) {
    unsigned u = __float_as_uint(f);
    return (unsigned short)((u + 0x7FFFu + ((u >> 16) & 1u)) >> 16);  // RNE
}

__global__ void k_zero_deg(int* __restrict__ deg, int N) {
    int i = blockIdx.x * blockDim.x + threadIdx.x;
    if (i < N) deg[i] = 0;
}

// ---------- fused: histogram(+rank) | layer-1 GEMM (unscaled) ----------
// hist blocks first (atomic-latency-bound, ~0.3% VALU); gemm backfills the idle machine.
__global__ __launch_bounds__(256, 4) void k_hist_gemm1(
        const int* __restrict__ dst, int* __restrict__ deg, int* __restrict__ rank,
        int E, int histBlocks,
        const float* __restrict__ h, const float* __restrict__ W,
        unsigned short* __restrict__ gbf, int N) {
    __shared__ float Wl[DFEAT * DFEAT];
    int tid = threadIdx.x;

    if ((int)blockIdx.x < histBlocks) {
        int t = blockIdx.x * blockDim.x + tid;
        int E4 = E >> 2;
        if (t < E4) {
            int4 d = reinterpret_cast<const int4*>(dst)[t];
            int4 r;
            r.x = atomicAdd(&deg[d.x], 1);
            r.y = atomicAdd(&deg[d.y], 1);
            r.z = atomicAdd(&deg[d.z], 1);
            r.w = atomicAdd(&deg[d.w], 1);
            reinterpret_cast<int4*>(rank)[t] = r;
        }
        if (t == 0) {
            for (int e = E4 * 4; e < E; ++e) rank[e] = atomicAdd(&deg[dst[e]], 1);
        }
        return;
    }

    // ---- gemm path: gbf[r][c] = bf16(h[r,:] @ W[:,c])  (dinv applied later) ----
    #pragma unroll
    for (int i = 0; i < 16; ++i) Wl[tid + i * 256] = W[tid + i * 256];
    __syncthreads();

    int r = (blockIdx.x - histBlocks) * 16 + (tid >> 4);
    if (r >= N) return;
    int c0 = (tid & 15) * 4;

    const float4* h4 = reinterpret_cast<const float4*>(h + (size_t)r * DFEAT);
    float4 hr[16];
    #pragma unroll
    for (int j = 0; j < 16; ++j) hr[j] = h4[j];

    float a0 = 0.f, a1 = 0.f, a2 = 0.f, a3 = 0.f;
    #pragma unroll
    for (int j = 0; j < 16; ++j) {
        float4 hv = hr[j];
        float4 w0 = *reinterpret_cast<const float4*>(&Wl[(4 * j + 0) * DFEAT + c0]);
        float4 w1 = *reinterpret_cast<const float4*>(&Wl[(4 * j + 1) * DFEAT + c0]);
        float4 w2 = *reinterpret_cast<const float4*>(&Wl[(4 * j + 2) * DFEAT + c0]);
        float4 w3 = *reinterpret_cast<const float4*>(&Wl[(4 * j + 3) * DFEAT + c0]);
        a0 = fmaf(hv.x, w0.x, a0); a1 = fmaf(hv.x, w0.y, a1);
        a2 = fmaf(hv.x, w0.z, a2); a3 = fmaf(hv.x, w0.w, a3);
        a0 = fmaf(hv.y, w1.x, a0); a1 = fmaf(hv.y, w1.y, a1);
        a2 = fmaf(hv.y, w1.z, a2); a3 = fmaf(hv.y, w1.w, a3);
        a0 = fmaf(hv.z, w2.x, a0); a1 = fmaf(hv.z, w2.y, a1);
        a2 = fmaf(hv.z, w2.z, a2); a3 = fmaf(hv.z, w2.w, a3);
        a0 = fmaf(hv.w, w3.x, a0); a1 = fmaf(hv.w, w3.y, a1);
        a2 = fmaf(hv.w, w3.z, a2); a3 = fmaf(hv.w, w3.w, a3);
    }
    ushort4 o;
    o.x = f2bf(a0); o.y = f2bf(a1); o.z = f2bf(a2); o.w = f2bf(a3);
    *reinterpret_cast<ushort4*>(&gbf[(size_t)r * DFEAT + c0]) = o;
}

// ---------- exclusive scan of deg -> rowstart (+ dinv fused) ----------
__global__ void k_scan_block(const int* __restrict__ deg, int* __restrict__ excl,
                             int* __restrict__ blockSums, float* __restrict__ dinv, int N) {
    __shared__ int sm[SCAN_B];
    int gid = blockIdx.x * SCAN_B + threadIdx.x;
    int v = (gid < N) ? deg[gid] : 0;
    if (gid < N) dinv[gid] = rsqrtf(1.0f + (float)v);  // +1 = self-loop
    sm[threadIdx.x] = v;
    __syncthreads();
    for (int off = 1; off < SCAN_B; off <<= 1) {
        int t = (threadIdx.x >= off) ? sm[threadIdx.x - off] : 0;
        __syncthreads();
        sm[threadIdx.x] += t;
        __syncthreads();
    }
    if (gid < N) excl[gid] = sm[threadIdx.x] - v;
    if (threadIdx.x == SCAN_B - 1) blockSums[blockIdx.x] = sm[threadIdx.x];
}

__global__ void k_scan_sums(int* __restrict__ blockSums, int nb) {
    __shared__ int sm[SCAN_B];
    int v = (threadIdx.x < nb) ? blockSums[threadIdx.x] : 0;
    sm[threadIdx.x] = v;
    __syncthreads();
    for (int off = 1; off < SCAN_B; off <<= 1) {
        int t = (threadIdx.x >= off) ? sm[threadIdx.x - off] : 0;
        __syncthreads();
        sm[threadIdx.x] += t;
        __syncthreads();
    }
    if (threadIdx.x < nb) blockSums[threadIdx.x] = sm[threadIdx.x] - v;  // exclusive
}

__global__ void k_add_offsets(const int* __restrict__ excl, const int* __restrict__ blockSums,
                              int* __restrict__ rowstart, int N, int E) {
    int gid = blockIdx.x * SCAN_B + threadIdx.x;
    if (gid < N) rowstart[gid] = excl[gid] + blockSums[blockIdx.x];
    else if (gid == N) rowstart[N] = E;
}

// ---------- fused: CSR fill (x4) | scale gbf by dinv[row] ----------
__global__ __launch_bounds__(256, 8) void k_fill_scale(
        const int* __restrict__ src, const int* __restrict__ dst,
        const int* __restrict__ rank, const int* __restrict__ rowstart,
        int* __restrict__ eid, int E, int fillBlocks,
        unsigned short* __restrict__ gbf, const float* __restrict__ dinv, int N) {
    int tid = threadIdx.x;
    if ((int)blockIdx.x < fillBlocks) {
        int t = blockIdx.x * blockDim.x + tid;
        int E4 = E >> 2;
        if (t < E4) {
            int4 s = reinterpret_cast<const int4*>(src)[t];
            int4 d = reinterpret_cast<const int4*>(dst)[t];
            int4 r = reinterpret_cast<const int4*>(rank)[t];
            eid[rowstart[d.x] + r.x] = s.x;
            eid[rowstart[d.y] + r.y] = s.y;
            eid[rowstart[d.z] + r.z] = s.z;
            eid[rowstart[d.w] + r.w] = s.w;
        }
        if (t == 0) {
            for (int e = E4 * 4; e < E; ++e) eid[rowstart[dst[e]] + rank[e]] = src[e];
        }
        return;
    }
    // scale path: gbf[r][c] *= dinv[r], 4 cols/thread
    int t = (blockIdx.x - fillBlocks) * blockDim.x + tid;
    if (t >= N * 16) return;
    int r = t >> 4;
    float di = dinv[r];
    ushort4 v = reinterpret_cast<ushort4*>(gbf)[t];
    v.x = f2bf(bf2f(v.x) * di);
    v.y = f2bf(bf2f(v.y) * di);
    v.z = f2bf(bf2f(v.z) * di);
    v.w = f2bf(bf2f(v.w) * di);
    reinterpret_cast<ushort4*>(gbf)[t] = v;
}

// ---------- fused: pull-aggregate + next-layer matvec ----------
// h = relu(dinv*acc + b) computed per node (1 val/lane); staged in per-wave LDS
// (wave-synchronous, no barrier); matvec vs LDS-resident Wn; writes next bf16 messages.
__global__ __launch_bounds__(256, 8) void k_agg_gemm(
        const unsigned short* __restrict__ g,
        const int* __restrict__ rowstart, const int* __restrict__ eid,
        const float* __restrict__ dinv, const float* __restrict__ b,
        const float* __restrict__ Wn, unsigned short* __restrict__ gout,
        int N, int npw) {
    __shared__ float Wl[DFEAT * DFEAT];
    __shared__ float hs[4][DFEAT];
    int tid = threadIdx.x;
    #pragma unroll
    for (int i = 0; i < 16; ++i) Wl[tid + i * 256] = Wn[tid + i * 256];
    __syncthreads();

    int wl = tid >> 6;           // wave within block
    int lane = tid & 63;
    int wv = (blockIdx.x * blockDim.x + tid) >> 6;
    int n0 = wv * npw;
    int n1 = n0 + npw; if (n1 > N) n1 = N;
    if (n0 >= N) return;
    float bias = b[lane];

    for (int node = n0; node < n1; ++node) {
        int s0 = __builtin_amdgcn_readfirstlane(rowstart[node]);
        int s1 = __builtin_amdgcn_readfirstlane(rowstart[node + 1]);

        float accA = bf2f(g[(size_t)node * DFEAT + lane]);  // self-loop term
        float accB = 0.f;
        int i = s0;
        for (; i + 8 <= s1; i += 8) {
            int e0 = eid[i + 0], e1 = eid[i + 1], e2 = eid[i + 2], e3 = eid[i + 3];
            int e4 = eid[i + 4], e5 = eid[i + 5], e6 = eid[i + 6], e7 = eid[i + 7];
            float v0 = bf2f(g[(size_t)e0 * DFEAT + lane]);
            float v1 = bf2f(g[(size_t)e1 * DFEAT + lane]);
            float v2 = bf2f(g[(size_t)e2 * DFEAT + lane]);
            float v3 = bf2f(g[(size_t)e3 * DFEAT + lane]);
            float v4 = bf2f(g[(size_t)e4 * DFEAT + lane]);
            float v5 = bf2f(g[(size_t)e5 * DFEAT + lane]);
            float v6 = bf2f(g[(size_t)e6 * DFEAT + lane]);
            float v7 = bf2f(g[(size_t)e7 * DFEAT + lane]);
            accA += (v0 + v1) + (v2 + v3);
            accB += (v4 + v5) + (v6 + v7);
        }
        for (; i + 2 <= s1; i += 2) {
            int e0 = eid[i], e1 = eid[i + 1];
            accA += bf2f(g[(size_t)e0 * DFEAT + lane]);
            accB += bf2f(g[(size_t)e1 * DFEAT + lane]);
        }
        if (i < s1) accA += bf2f(g[(size_t)eid[i] * DFEAT + lane]);

        float h = fmaxf(fmaf(dinv[node], accA + accB, bias), 0.f);
        hs[wl][lane] = h;  // wave-synchronous LDS exchange (no barrier)

        float m0 = 0.f, m1 = 0.f;
        #pragma unroll
        for (int k4 = 0; k4 < 16; ++k4) {
            float4 hv = *reinterpret_cast<const float4*>(&hs[wl][k4 * 4]);  // broadcast
            m0 = fmaf(hv.x, Wl[(4 * k4 + 0) * DFEAT + lane], m0);
            m1 = fmaf(hv.y, Wl[(4 * k4 + 1) * DFEAT + lane], m1);
            m0 = fmaf(hv.z, Wl[(4 * k4 + 2) * DFEAT + lane], m0);
            m1 = fmaf(hv.w, Wl[(4 * k4 + 3) * DFEAT + lane], m1);
        }
        gout[(size_t)node * DFEAT + lane] = f2bf((m0 + m1) * dinv[node]);
    }
}

// ---------- final aggregate (layer 3): writes f32 out ----------
__global__ __launch_bounds__(256, 8) void k_agg_final(
        const unsigned short* __restrict__ g,
        const int* __restrict__ rowstart, const int* __restrict__ eid,
        const float* __restrict__ dinv, const float* __restrict__ b,
        float* __restrict__ hout, int N, int npw) {
    int wv = (blockIdx.x * blockDim.x + threadIdx.x) >> 6;
    int lane = threadIdx.x & 63;
    int n0 = wv * npw;
    int n1 = n0 + npw; if (n1 > N) n1 = N;
    if (n0 >= N) return;
    float bias = b[lane];

    for (int node = n0; node < n1; ++node) {
        int s0 = __builtin_amdgcn_readfirstlane(rowstart[node]);
        int s1 = __builtin_amdgcn_readfirstlane(rowstart[node + 1]);

        float accA = bf2f(g[(size_t)node * DFEAT + lane]);
        float accB = 0.f;
        int i = s0;
        for (; i + 8 <= s1; i += 8) {
            int e0 = eid[i + 0], e1 = eid[i + 1], e2 = eid[i + 2], e3 = eid[i + 3];
            int e4 = eid[i + 4], e5 = eid[i + 5], e6 = eid[i + 6], e7 = eid[i + 7];
            float v0 = bf2f(g[(size_t)e0 * DFEAT + lane]);
            float v1 = bf2f(g[(size_t)e1 * DFEAT + lane]);
            float v2 = bf2f(g[(size_t)e2 * DFEAT + lane]);
            float v3 = bf2f(g[(size_t)e3 * DFEAT + lane]);
            float v4 = bf2f(g[(size_t)e4 * DFEAT + lane]);
            float v5 = bf2f(g[(size_t)e5 * DFEAT + lane]);
            float v6 = bf2f(g[(size_t)e6 * DFEAT + lane]);
            float v7 = bf2f(g[(size_t)e7 * DFEAT + lane]);
            accA += (v0 + v1) + (v2 + v3);
            accB += (v4 + v5) + (v6 + v7);
        }
        for (; i + 2 <= s1; i += 2) {
            int e0 = eid[i], e1 = eid[i + 1];
            accA += bf2f(g[(size_t)e0 * DFEAT + lane]);
            accB += bf2f(g[(size_t)e1 * DFEAT + lane]);
        }
        if (i < s1) accA += bf2f(g[(size_t)eid[i] * DFEAT + lane]);

        hout[(size_t)node * DFEAT + lane] = fmaxf(fmaf(dinv[node], accA + accB, bias), 0.f);
    }
}

extern "C" void kernel_launch(void* const* d_in, const int* in_sizes, int n_in,
                              void* d_out, int out_size, void* d_ws, size_t ws_size,
                              hipStream_t stream) {
    const float* x  = (const float*)d_in[0];
    const float* W1 = (const float*)d_in[1];
    const float* b1 = (const float*)d_in[2];
    const float* W2 = (const float*)d_in[3];
    const float* b2 = (const float*)d_in[4];
    const float* W3 = (const float*)d_in[5];
    const float* b3 = (const float*)d_in[6];
    const int* eidx = (const int*)d_in[7];  // int64 under default JAX -> int32

    const int N = in_sizes[0] / DFEAT;   // 100000
    const int E = in_sizes[7] / 2;       // 1000000
    const int* esrc = eidx;
    const int* edst = eidx + E;

    // workspace layout (64B-aligned chunks)
    auto align64 = [](size_t v) { return (v + 63) & ~(size_t)63; };
    char* wp = (char*)d_ws;
    int*   deg       = (int*)wp;              wp += align64((size_t)N * 4);
    float* dinv      = (float*)wp;            wp += align64((size_t)N * 4);
    int*   excl      = (int*)wp;              wp += align64((size_t)N * 4);
    int*   blockSums = (int*)wp;              wp += align64((size_t)SCAN_B * 4);
    int*   rowstart  = (int*)wp;              wp += align64((size_t)(N + 1) * 4);
    int*   rank      = (int*)wp;              wp += align64((size_t)E * 4);
    int*   eid       = (int*)wp;              wp += align64((size_t)E * 4);
    unsigned short* gbfA = (unsigned short*)wp; wp += align64((size_t)N * DFEAT * 2);
    unsigned short* gbfB = (unsigned short*)wp; wp += align64((size_t)N * DFEAT * 2);
    float* out = (float*)d_out;

    const int B = 256;
    const int nScanBlocks = (N + SCAN_B) / SCAN_B + 1;  // covers gid==N

    const int histBlocks  = ((E >> 2) + B - 1) / B;     // 977
    const int fillBlocks  = histBlocks;
    const int gemm_grid   = (N + 15) / 16;              // 6250
    const int scaleBlocks = (N * 16 + B - 1) / B;       // 6250

    const int agg_blocks = 2048;                        // 8192 waves
    const int npw = (N + agg_blocks * 4 - 1) / (agg_blocks * 4);  // 13

    k_zero_deg<<<(N + B - 1) / B, B, 0, stream>>>(deg, N);
    // hist || gemm1 (unscaled)
    k_hist_gemm1<<<histBlocks + gemm_grid, B, 0, stream>>>(
        edst, deg, rank, E, histBlocks, x, W1, gbfA, N);
    // scan (+dinv)
    k_scan_block<<<(N + SCAN_B - 1) / SCAN_B, SCAN_B, 0, stream>>>(deg, excl, blockSums, dinv, N);
    k_scan_sums<<<1, SCAN_B, 0, stream>>>(blockSums, (N + SCAN_B - 1) / SCAN_B);
    k_add_offsets<<<nScanBlocks, SCAN_B, 0, stream>>>(excl, blockSums, rowstart, N, E);
    // fill || scale gbfA by dinv
    k_fill_scale<<<fillBlocks + scaleBlocks, B, 0, stream>>>(
        esrc, edst, rank, rowstart, eid, E, fillBlocks, gbfA, dinv, N);
    // layer 1 aggregate + layer 2 gemm fused
    k_agg_gemm<<<agg_blocks, B, 0, stream>>>(gbfA, rowstart, eid, dinv, b1, W2, gbfB, N, npw);
    // layer 2 aggregate + layer 3 gemm fused
    k_agg_gemm<<<agg_blocks, B, 0, stream>>>(gbfB, rowstart, eid, dinv, b2, W3, gbfA, N, npw);
    // layer 3 aggregate -> out
    k_agg_final<<<agg_blocks, B, 0, stream>>>(gbfA, rowstart, eid, dinv, b3, out, N, npw);
}

// Round 9
// 284.342 us; speedup vs baseline: 1.5961x; 1.5961x over previous
//
#include <hip/hip_runtime.h>

#define DFEAT 64
#define SCAN_B 1024

__device__ __forceinline__ float bf2f(unsigned short u) {
    return __uint_as_float(((unsigned)u) << 16);
}
__device__ __forceinline__ unsigned short f2bf(float f) {
    unsigned u = __float_as_uint(f);
    return (unsigned short)((u + 0x7FFFu + ((u >> 16) & 1u)) >> 16);  // RNE
}

__global__ void k_zero_deg(int* __restrict__ deg, int N) {
    int i = blockIdx.x * blockDim.x + threadIdx.x;
    if (i < N) deg[i] = 0;
}

// ---------- fused: histogram(+rank) | layer-1 GEMM (unscaled) ----------
__global__ __launch_bounds__(256, 4) void k_hist_gemm1(
        const int* __restrict__ dst, int* __restrict__ deg, int* __restrict__ rank,
        int E, int histBlocks,
        const float* __restrict__ h, const float* __restrict__ W,
        unsigned short* __restrict__ gbf, int N) {
    __shared__ float Wl[DFEAT * DFEAT];
    int tid = threadIdx.x;

    if ((int)blockIdx.x < histBlocks) {
        int t = blockIdx.x * blockDim.x + tid;
        int E4 = E >> 2;
        if (t < E4) {
            int4 d = reinterpret_cast<const int4*>(dst)[t];
            int4 r;
            r.x = atomicAdd(&deg[d.x], 1);
            r.y = atomicAdd(&deg[d.y], 1);
            r.z = atomicAdd(&deg[d.z], 1);
            r.w = atomicAdd(&deg[d.w], 1);
            reinterpret_cast<int4*>(rank)[t] = r;
        }
        if (t == 0) {
            for (int e = E4 * 4; e < E; ++e) rank[e] = atomicAdd(&deg[dst[e]], 1);
        }
        return;
    }

    // gemm path: gbf[r][c] = bf16(h[r,:] @ W[:,c])   (dinv applied later)
    #pragma unroll
    for (int i = 0; i < 16; ++i) Wl[tid + i * 256] = W[tid + i * 256];
    __syncthreads();

    int r = (blockIdx.x - histBlocks) * 16 + (tid >> 4);
    if (r >= N) return;
    int c0 = (tid & 15) * 4;

    const float4* h4 = reinterpret_cast<const float4*>(h + (size_t)r * DFEAT);
    float4 hr[16];
    #pragma unroll
    for (int j = 0; j < 16; ++j) hr[j] = h4[j];

    float a0 = 0.f, a1 = 0.f, a2 = 0.f, a3 = 0.f;
    #pragma unroll
    for (int j = 0; j < 16; ++j) {
        float4 hv = hr[j];
        float4 w0 = *reinterpret_cast<const float4*>(&Wl[(4 * j + 0) * DFEAT + c0]);
        float4 w1 = *reinterpret_cast<const float4*>(&Wl[(4 * j + 1) * DFEAT + c0]);
        float4 w2 = *reinterpret_cast<const float4*>(&Wl[(4 * j + 2) * DFEAT + c0]);
        float4 w3 = *reinterpret_cast<const float4*>(&Wl[(4 * j + 3) * DFEAT + c0]);
        a0 = fmaf(hv.x, w0.x, a0); a1 = fmaf(hv.x, w0.y, a1);
        a2 = fmaf(hv.x, w0.z, a2); a3 = fmaf(hv.x, w0.w, a3);
        a0 = fmaf(hv.y, w1.x, a0); a1 = fmaf(hv.y, w1.y, a1);
        a2 = fmaf(hv.y, w1.z, a2); a3 = fmaf(hv.y, w1.w, a3);
        a0 = fmaf(hv.z, w2.x, a0); a1 = fmaf(hv.z, w2.y, a1);
        a2 = fmaf(hv.z, w2.z, a2); a3 = fmaf(hv.z, w2.w, a3);
        a0 = fmaf(hv.w, w3.x, a0); a1 = fmaf(hv.w, w3.y, a1);
        a2 = fmaf(hv.w, w3.z, a2); a3 = fmaf(hv.w, w3.w, a3);
    }
    ushort4 o;
    o.x = f2bf(a0); o.y = f2bf(a1); o.z = f2bf(a2); o.w = f2bf(a3);
    *reinterpret_cast<ushort4*>(&gbf[(size_t)r * DFEAT + c0]) = o;
}

// ---------- exclusive scan of deg -> rowstart (+ dinv fused) ----------
__global__ void k_scan_block(const int* __restrict__ deg, int* __restrict__ excl,
                             int* __restrict__ blockSums, float* __restrict__ dinv, int N) {
    __shared__ int sm[SCAN_B];
    int gid = blockIdx.x * SCAN_B + threadIdx.x;
    int v = (gid < N) ? deg[gid] : 0;
    if (gid < N) dinv[gid] = rsqrtf(1.0f + (float)v);  // +1 = self-loop
    sm[threadIdx.x] = v;
    __syncthreads();
    for (int off = 1; off < SCAN_B; off <<= 1) {
        int t = (threadIdx.x >= off) ? sm[threadIdx.x - off] : 0;
        __syncthreads();
        sm[threadIdx.x] += t;
        __syncthreads();
    }
    if (gid < N) excl[gid] = sm[threadIdx.x] - v;
    if (threadIdx.x == SCAN_B - 1) blockSums[blockIdx.x] = sm[threadIdx.x];
}

__global__ void k_scan_sums(int* __restrict__ blockSums, int nb) {
    __shared__ int sm[SCAN_B];
    int v = (threadIdx.x < nb) ? blockSums[threadIdx.x] : 0;
    sm[threadIdx.x] = v;
    __syncthreads();
    for (int off = 1; off < SCAN_B; off <<= 1) {
        int t = (threadIdx.x >= off) ? sm[threadIdx.x - off] : 0;
        __syncthreads();
        sm[threadIdx.x] += t;
        __syncthreads();
    }
    if (threadIdx.x < nb) blockSums[threadIdx.x] = sm[threadIdx.x] - v;  // exclusive
}

__global__ void k_add_offsets(const int* __restrict__ excl, const int* __restrict__ blockSums,
                              int* __restrict__ rowstart, int N, int E) {
    int gid = blockIdx.x * SCAN_B + threadIdx.x;
    if (gid < N) rowstart[gid] = excl[gid] + blockSums[blockIdx.x];
    else if (gid == N) rowstart[N] = E;
}

// ---------- fused: CSR fill (x4) | scale gbf by dinv[row] ----------
__global__ __launch_bounds__(256, 8) void k_fill_scale(
        const int* __restrict__ src, const int* __restrict__ dst,
        const int* __restrict__ rank, const int* __restrict__ rowstart,
        int* __restrict__ eid, int E, int fillBlocks,
        unsigned short* __restrict__ gbf, const float* __restrict__ dinv, int N) {
    int tid = threadIdx.x;
    if ((int)blockIdx.x < fillBlocks) {
        int t = blockIdx.x * blockDim.x + tid;
        int E4 = E >> 2;
        if (t < E4) {
            int4 s = reinterpret_cast<const int4*>(src)[t];
            int4 d = reinterpret_cast<const int4*>(dst)[t];
            int4 r = reinterpret_cast<const int4*>(rank)[t];
            eid[rowstart[d.x] + r.x] = s.x;
            eid[rowstart[d.y] + r.y] = s.y;
            eid[rowstart[d.z] + r.z] = s.z;
            eid[rowstart[d.w] + r.w] = s.w;
        }
        if (t == 0) {
            for (int e = E4 * 4; e < E; ++e) eid[rowstart[dst[e]] + rank[e]] = src[e];
        }
        return;
    }
    int t = (blockIdx.x - fillBlocks) * blockDim.x + tid;
    if (t >= N * 16) return;
    int r = t >> 4;
    float di = dinv[r];
    ushort4 v = reinterpret_cast<ushort4*>(gbf)[t];
    v.x = f2bf(bf2f(v.x) * di);
    v.y = f2bf(bf2f(v.y) * di);
    v.z = f2bf(bf2f(v.z) * di);
    v.w = f2bf(bf2f(v.w) * di);
    reinterpret_cast<ushort4*>(gbf)[t] = v;
}

// ---------- standalone GEMM (layers 2,3): gbf = bf16((h @ W) * dinv) ----------
__global__ __launch_bounds__(256, 4) void k_gemm_scale(
        const float* __restrict__ h, const float* __restrict__ W,
        const float* __restrict__ dinv, unsigned short* __restrict__ gbf, int N) {
    __shared__ float Wl[DFEAT * DFEAT];
    int tid = threadIdx.x;
    #pragma unroll
    for (int i = 0; i < 16; ++i) Wl[tid + i * 256] = W[tid + i * 256];
    __syncthreads();

    int r = blockIdx.x * 16 + (tid >> 4);
    if (r >= N) return;
    int c0 = (tid & 15) * 4;

    const float4* h4 = reinterpret_cast<const float4*>(h + (size_t)r * DFEAT);
    float4 hr[16];
    #pragma unroll
    for (int j = 0; j < 16; ++j) hr[j] = h4[j];

    float a0 = 0.f, a1 = 0.f, a2 = 0.f, a3 = 0.f;
    #pragma unroll
    for (int j = 0; j < 16; ++j) {
        float4 hv = hr[j];
        float4 w0 = *reinterpret_cast<const float4*>(&Wl[(4 * j + 0) * DFEAT + c0]);
        float4 w1 = *reinterpret_cast<const float4*>(&Wl[(4 * j + 1) * DFEAT + c0]);
        float4 w2 = *reinterpret_cast<const float4*>(&Wl[(4 * j + 2) * DFEAT + c0]);
        float4 w3 = *reinterpret_cast<const float4*>(&Wl[(4 * j + 3) * DFEAT + c0]);
        a0 = fmaf(hv.x, w0.x, a0); a1 = fmaf(hv.x, w0.y, a1);
        a2 = fmaf(hv.x, w0.z, a2); a3 = fmaf(hv.x, w0.w, a3);
        a0 = fmaf(hv.y, w1.x, a0); a1 = fmaf(hv.y, w1.y, a1);
        a2 = fmaf(hv.y, w1.z, a2); a3 = fmaf(hv.y, w1.w, a3);
        a0 = fmaf(hv.z, w2.x, a0); a1 = fmaf(hv.z, w2.y, a1);
        a2 = fmaf(hv.z, w2.z, a2); a3 = fmaf(hv.z, w2.w, a3);
        a0 = fmaf(hv.w, w3.x, a0); a1 = fmaf(hv.w, w3.y, a1);
        a2 = fmaf(hv.w, w3.z, a2); a3 = fmaf(hv.w, w3.w, a3);
    }
    float di = dinv[r];
    ushort4 o;
    o.x = f2bf(a0 * di); o.y = f2bf(a1 * di);
    o.z = f2bf(a2 * di); o.w = f2bf(a3 * di);
    *reinterpret_cast<ushort4*>(&gbf[(size_t)r * DFEAT + c0]) = o;
}

// ---------- pull-aggregate: half-wave per neighbor-list-half, 4B/lane ----------
// One vmem instruction gathers TWO rows (one per half-wave). Lane hl handles
// features {2*hl, 2*hl+1}. Combine halves via shfl_xor(32).
__global__ __launch_bounds__(256, 8) void k_agg(
        const unsigned short* __restrict__ g,
        const int* __restrict__ rowstart, const int* __restrict__ eid,
        const float* __restrict__ dinv, const float* __restrict__ b,
        float* __restrict__ hout, int N, int npw) {
    int tid = threadIdx.x;
    int wv = (blockIdx.x * blockDim.x + tid) >> 6;
    int lane = tid & 63;
    int hl = lane & 31;
    bool hi = lane >= 32;
    int n0 = wv * npw;
    int n1 = n0 + npw; if (n1 > N) n1 = N;
    if (n0 >= N) return;
    float2 bias = *reinterpret_cast<const float2*>(&b[2 * hl]);
    const unsigned* g32 = reinterpret_cast<const unsigned*>(g);

    for (int node = n0; node < n1; ++node) {
        int s0 = __builtin_amdgcn_readfirstlane(rowstart[node]);
        int s1 = __builtin_amdgcn_readfirstlane(rowstart[node + 1]);
        int mid = (s0 + s1 + 1) >> 1;          // lo half [s0,mid), hi half [mid,s1)
        int kmax = mid - s0;                   // lo size >= hi size (by <=1)
        int beg = hi ? mid : s0;
        int end = hi ? s1 : mid;

        float ax = 0.f, ay = 0.f;
        int k = 0;
        for (; k + 4 <= kmax; k += 4) {
            int i0 = beg + k, i1 = beg + k + 1, i2 = beg + k + 2, i3 = beg + k + 3;
            bool v0 = i0 < end, v1 = i1 < end, v2 = i2 < end, v3 = i3 < end;
            int e0 = eid[v0 ? i0 : s0];
            int e1 = eid[v1 ? i1 : s0];
            int e2 = eid[v2 ? i2 : s0];
            int e3 = eid[v3 ? i3 : s0];
            unsigned u0 = g32[(size_t)e0 * 32 + hl];
            unsigned u1 = g32[(size_t)e1 * 32 + hl];
            unsigned u2 = g32[(size_t)e2 * 32 + hl];
            unsigned u3 = g32[(size_t)e3 * 32 + hl];
            if (v0) { ax += bf2f((unsigned short)u0); ay += bf2f((unsigned short)(u0 >> 16)); }
            if (v1) { ax += bf2f((unsigned short)u1); ay += bf2f((unsigned short)(u1 >> 16)); }
            if (v2) { ax += bf2f((unsigned short)u2); ay += bf2f((unsigned short)(u2 >> 16)); }
            if (v3) { ax += bf2f((unsigned short)u3); ay += bf2f((unsigned short)(u3 >> 16)); }
        }
        for (; k < kmax; ++k) {
            int i0 = beg + k;
            bool v0 = i0 < end;
            int e0 = eid[v0 ? i0 : s0];
            unsigned u0 = g32[(size_t)e0 * 32 + hl];
            if (v0) { ax += bf2f((unsigned short)u0); ay += bf2f((unsigned short)(u0 >> 16)); }
        }

        // combine the two halves
        ax += __shfl_xor(ax, 32, 64);
        ay += __shfl_xor(ay, 32, 64);

        // self-loop term (added once, after combine)
        unsigned us = g32[(size_t)node * 32 + hl];
        ax += bf2f((unsigned short)us);
        ay += bf2f((unsigned short)(us >> 16));

        float di = dinv[node];
        if (!hi) {
            float2 o;
            o.x = fmaxf(fmaf(di, ax, bias.x), 0.f);
            o.y = fmaxf(fmaf(di, ay, bias.y), 0.f);
            *reinterpret_cast<float2*>(&hout[(size_t)node * DFEAT + 2 * hl]) = o;
        }
    }
}

extern "C" void kernel_launch(void* const* d_in, const int* in_sizes, int n_in,
                              void* d_out, int out_size, void* d_ws, size_t ws_size,
                              hipStream_t stream) {
    const float* x  = (const float*)d_in[0];
    const float* W1 = (const float*)d_in[1];
    const float* b1 = (const float*)d_in[2];
    const float* W2 = (const float*)d_in[3];
    const float* b2 = (const float*)d_in[4];
    const float* W3 = (const float*)d_in[5];
    const float* b3 = (const float*)d_in[6];
    const int* eidx = (const int*)d_in[7];  // int64 under default JAX -> int32

    const int N = in_sizes[0] / DFEAT;   // 100000
    const int E = in_sizes[7] / 2;       // 1000000
    const int* esrc = eidx;
    const int* edst = eidx + E;

    auto align64 = [](size_t v) { return (v + 63) & ~(size_t)63; };
    char* wp = (char*)d_ws;
    int*   deg       = (int*)wp;              wp += align64((size_t)N * 4);
    float* dinv      = (float*)wp;            wp += align64((size_t)N * 4);
    int*   excl      = (int*)wp;              wp += align64((size_t)N * 4);
    int*   blockSums = (int*)wp;              wp += align64((size_t)SCAN_B * 4);
    int*   rowstart  = (int*)wp;              wp += align64((size_t)(N + 1) * 4);
    int*   rank      = (int*)wp;              wp += align64((size_t)E * 4);
    int*   eid       = (int*)wp;              wp += align64((size_t)E * 4);
    unsigned short* gbfA = (unsigned short*)wp; wp += align64((size_t)N * DFEAT * 2);
    unsigned short* gbfB = (unsigned short*)wp; wp += align64((size_t)N * DFEAT * 2);
    float* hbuf      = (float*)wp;            wp += align64((size_t)N * DFEAT * 4);
    float* out = (float*)d_out;

    const int B = 256;
    const int nScanBlocks = (N + SCAN_B) / SCAN_B + 1;

    const int histBlocks  = ((E >> 2) + B - 1) / B;     // 977
    const int fillBlocks  = histBlocks;
    const int gemm_grid   = (N + 15) / 16;              // 6250
    const int scaleBlocks = (N * 16 + B - 1) / B;       // 6250

    const int agg_blocks = 2048;                        // 8192 waves
    const int npw = (N + agg_blocks * 4 - 1) / (agg_blocks * 4);  // 13

    k_zero_deg<<<(N + B - 1) / B, B, 0, stream>>>(deg, N);
    // hist || gemm1 (unscaled)
    k_hist_gemm1<<<histBlocks + gemm_grid, B, 0, stream>>>(
        edst, deg, rank, E, histBlocks, x, W1, gbfA, N);
    // scan (+dinv)
    k_scan_block<<<(N + SCAN_B - 1) / SCAN_B, SCAN_B, 0, stream>>>(deg, excl, blockSums, dinv, N);
    k_scan_sums<<<1, SCAN_B, 0, stream>>>(blockSums, (N + SCAN_B - 1) / SCAN_B);
    k_add_offsets<<<nScanBlocks, SCAN_B, 0, stream>>>(excl, blockSums, rowstart, N, E);
    // fill || scale gbfA by dinv
    k_fill_scale<<<fillBlocks + scaleBlocks, B, 0, stream>>>(
        esrc, edst, rank, rowstart, eid, E, fillBlocks, gbfA, dinv, N);

    // layer 1
    k_agg<<<agg_blocks, B, 0, stream>>>(gbfA, rowstart, eid, dinv, b1, hbuf, N, npw);
    // layer 2
    k_gemm_scale<<<gemm_grid, B, 0, stream>>>(hbuf, W2, dinv, gbfB, N);
    k_agg<<<agg_blocks, B, 0, stream>>>(gbfB, rowstart, eid, dinv, b2, hbuf, N, npw);
    // layer 3
    k_gemm_scale<<<gemm_grid, B, 0, stream>>>(hbuf, W3, dinv, gbfA, N);
    k_agg<<<agg_blocks, B, 0, stream>>>(gbfA, rowstart, eid, dinv, b3, out, N, npw);
}